// Round 15
// baseline (68.526 us; speedup 1.0000x reference)
//
#include <hip/hip_runtime.h>
#include <stdint.h>

// Multihead_Attention on MI355X (gfx950). R14 base (67.67 µs) + non-GEMM micro
// consolidation: cvt 1152 blocks x 128B/thread (was 6912 x 16B: latency-bound),
// softmax 4 rows/block (512 blocks), transpose 4 tiles/block (final launch =
// 256 PV + 256 TR = exactly 2 blocks/CU).
// GEMM core unchanged (converged): bf16 MFMA 16x16x32, BK=64, BN=64, 512 thr,
// 3-buffer LDS / 1 barrier/iter, global_load_lds w16, counted vmcnt, setprio,
// XOR chunk swizzle, XCD rect swizzle.

#define TQ 2048
#define TK 2048
#define HD 1024

#define DEVI __device__ __forceinline__

typedef __attribute__((ext_vector_type(8))) short bf16x8;
typedef __attribute__((ext_vector_type(4))) float f32x4;
typedef __attribute__((ext_vector_type(4))) unsigned short u16x4;

DEVI unsigned short f2bf(float f) {
  uint32_t u = __builtin_bit_cast(uint32_t, f);
  u += 0x7FFFu + ((u >> 16) & 1u);
  return (unsigned short)(u >> 16);
}
DEVI float bf2f(unsigned short h) {
  uint32_t u = ((uint32_t)h) << 16;
  return __builtin_bit_cast(float, u);
}
DEVI void gload_lds16(const void* g, void* l) {
  __builtin_amdgcn_global_load_lds((const __attribute__((address_space(1))) void*)g,
                                   (__attribute__((address_space(3))) void*)l,
                                   16, 0, 0);
}
template<int N> DEVI void wait_vm() { asm volatile("s_waitcnt vmcnt(%0)" :: "n"(N) : "memory"); }
DEVI void wait_lgkm0() { asm volatile("s_waitcnt lgkmcnt(0)" ::: "memory"); }
#define SBAR() __builtin_amdgcn_s_barrier()

// ---- stage one K-step tile pair (A 128x64, B BNx64 bf16) into one LDS buffer.
template<int BN>
DEVI void stageT(const unsigned short* __restrict__ A, const unsigned short* __restrict__ B,
                 int lda, int ldb, int k0, unsigned short* buf, int tid) {
#pragma unroll
  for (int i = 0; i < 2; i++) {              // A: 128 rows x 8 chunks = 1024 chunks
    int c = i * 512 + tid;
    int r = c >> 3;
    int cs = (c & 7) ^ (r & 7);
    gload_lds16(A + (size_t)r * lda + k0 + cs * 8, buf + c * 8);
  }
#pragma unroll
  for (int i = 0; i < BN / 64; i++) {        // B: BN rows x 8 chunks
    int c = i * 512 + tid;
    int r = c >> 3;
    int cs = (c & 7) ^ (r & 7);
    gload_lds16(B + (size_t)r * ldb + k0 + cs * 8, buf + 8192 + c * 8);
  }
}

// ---- one staged 64-K-step. BN=128: wave 64x32 (acc[4][2]); BN=64: 32x32 (acc[2][2]).
template<int BN>
DEVI void computeT(const unsigned short* lA, const unsigned short* lB, f32x4 (*acc)[2],
                   int wr, int wc, int l15, int hi) {
  constexpr int FM = (BN == 128) ? 4 : 2;
  constexpr int WMR = (BN == 128) ? 64 : 32;
#pragma unroll
  for (int kk = 0; kk < 2; kk++) {
    bf16x8 af[4], bfr[2];
#pragma unroll
    for (int f = 0; f < FM; f++) {
      int ra = wr * WMR + f * 16 + l15;
      int ca = (kk * 4 + hi) ^ (ra & 7);
      af[f] = *(const bf16x8*)(lA + ra * 64 + ca * 8);
    }
#pragma unroll
    for (int f = 0; f < 2; f++) {
      int rb = wc * 32 + f * 16 + l15;
      int cb = (kk * 4 + hi) ^ (rb & 7);
      bfr[f] = *(const bf16x8*)(lB + rb * 64 + cb * 8);
    }
#pragma unroll
    for (int fm = 0; fm < FM; fm++)
#pragma unroll
      for (int fn = 0; fn < 2; fn++)
        acc[fm][fn] = __builtin_amdgcn_mfma_f32_16x16x32_bf16(af[fm], bfr[fn], acc[fm][fn], 0, 0, 0);
  }
}

// ---- 3-buffer pipeline, counted vmcnt, ONE barrier/iter, stage-before-compute.
// Ledger: RAW — wave Y's wait_vm<LPS> at iter t retires its stage(t) loads (only
// stage(t+1) outstanding) before Y enters SBAR(t); readers proceed after SBAR(t).
// WAR — stage(t+2) overwrites buf[(t-1)%3]; each wave's reads of it drained at its
// lgkm0 (end of iter t-1), which precedes its SBAR(t); the stage is issued only
// after SBAR(t). WAW — distinct buffers within any 2-deep window.
template<int BN, int NKT>
DEVI void mfma_pipeline(const unsigned short* __restrict__ A, const unsigned short* __restrict__ B,
                        int lda, int ldb, unsigned short* lds, f32x4 (*acc)[2]) {
  constexpr int FM = (BN == 128) ? 4 : 2;
  constexpr int LPS = 2 + BN / 64;           // loads per stage per thread (4 or 3)
  constexpr int BSTR = 8192 + BN * 64;       // buffer stride in shorts
  const int tid = threadIdx.x;
  const int lane = tid & 63, wave = tid >> 6;
  const int l15 = lane & 15, hi = lane >> 4;
  const int wr = (BN == 128) ? (wave >> 2) : (wave >> 1);
  const int wc = (BN == 128) ? (wave & 3) : (wave & 1);

#pragma unroll
  for (int i = 0; i < FM; i++)
#pragma unroll
    for (int j = 0; j < 2; j++) acc[i][j] = (f32x4)(0.0f);

  stageT<BN>(A, B, lda, ldb, 0, lds, tid);
  stageT<BN>(A, B, lda, ldb, 64, lds + BSTR, tid);

  int cur = 0, nxt = 2;                      // t%3 and (t+2)%3 counters
#pragma unroll 1
  for (int t = 0; t < NKT; ++t) {
    if (t < NKT - 1) wait_vm<LPS>();
    else wait_vm<0>();
    SBAR();                                   // buf t ready on every wave
    unsigned short* buf = lds + cur * BSTR;
    if (t + 2 < NKT) stageT<BN>(A, B, lda, ldb, (t + 2) * 64, lds + nxt * BSTR, tid);
    __builtin_amdgcn_s_setprio(1);
    computeT<BN>(buf, buf + 8192, acc, wr, wc, l15, hi);
    __builtin_amdgcn_s_setprio(0);
    wait_lgkm0();                             // my ds_reads drained (WAR release)
    cur = (cur == 2) ? 0 : cur + 1;
    nxt = (nxt == 2) ? 0 : nxt + 1;
  }
}

// ------------- batched projection: relu(X @ W^T + b), BN=64, 768 blocks ------------
__global__ __launch_bounds__(512, 4)
void gemm_proj(const unsigned short* __restrict__ Qb, const unsigned short* __restrict__ Kb,
               const unsigned short* __restrict__ Vb,
               const unsigned short* __restrict__ Wqb, const unsigned short* __restrict__ Wkb,
               const unsigned short* __restrict__ Wvb,
               const float* __restrict__ bq, const float* __restrict__ bk,
               const float* __restrict__ bv, const float* __restrict__ Wo,
               unsigned short* __restrict__ Ql, unsigned short* __restrict__ Ks,
               unsigned short* __restrict__ VT) {
  __shared__ __align__(16) unsigned short lds[3 * 12288];  // 72 KB
  const int bid = blockIdx.x;
  const int x = bid & 7, j = bid >> 3;       // XCD, index within (96 per XCD)
  const int z = j >> 5;                      // matrix select (32 tiles per z per XCD)
  const int jj = j & 31;
  const int bm = (x & 3) * 4 + (jj >> 3);    // [0,16) M-panel (128 rows)
  const int bn = (x >> 2) * 8 + (jj & 7);    // [0,16) 64-wide N-panel

  const unsigned short* A = (z == 0) ? Qb : (z == 1) ? Kb : Vb;
  const unsigned short* B = (z == 0) ? Wqb : (z == 1) ? Wkb : Wvb;
  const float* bias = (z == 0) ? bq : (z == 1) ? bk : bv;

  f32x4 acc[2][2];
  mfma_pipeline<64, 16>(A + (size_t)bm * 128 * HD, B + (size_t)bn * 64 * HD, HD, HD, lds, acc);

  const int tid = threadIdx.x;
  const int lane = tid & 63, wave = tid >> 6;
  const int wr = wave >> 1, wc = wave & 1;
  const int l15 = lane & 15, hi = lane >> 4;
  const int row0 = bm * 128 + wr * 32;
  const int col0 = bn * 64 + wc * 32;

  if (z == 2) {
    // V: LDS-transpose the 128x64 output tile -> coalesced VT row stores.
    __syncthreads();                          // all MFMA reads done before reuse
    unsigned short (*T)[132] = reinterpret_cast<unsigned short (*)[132]>(lds);
#pragma unroll
    for (int fm = 0; fm < 2; fm++)
#pragma unroll
      for (int fn = 0; fn < 2; fn++) {
        int cl = wc * 32 + fn * 16 + l15;     // local col [0,64)
        float b = bias[bn * 64 + cl];
#pragma unroll
        for (int i = 0; i < 4; i++)
          T[cl][wr * 32 + fm * 16 + hi * 4 + i] = f2bf(fmaxf(acc[fm][fn][i] + b, 0.0f));
      }
    __syncthreads();
#pragma unroll
    for (int i = 0; i < 4; i++) {
      int h = i * 512 + tid;                  // 2048 u16x4 chunks
      int c = h >> 5;                         // [0,64) local col -> VT row
      int rq = h & 31;                        // quad within 128-row run
      u16x4 v = *(const u16x4*)(&T[c][rq * 4]);
      *(u16x4*)(VT + (size_t)(bn * 64 + c) * TK + bm * 128 + rq * 4) = v;
    }
  } else {
#pragma unroll
    for (int fm = 0; fm < 2; fm++)
#pragma unroll
      for (int fn = 0; fn < 2; fn++) {
        int cg = col0 + fn * 16 + l15;
        int rg = row0 + fm * 16 + hi * 4;
        float b = bias[cg];
        if (z == 1) {
          float s = 0.125f * Wo[cg >> 6];     // fold Wo/sqrt(64) into K columns
#pragma unroll
          for (int i = 0; i < 4; i++)
            Ks[(size_t)(rg + i) * HD + cg] = f2bf(fmaxf(acc[fm][fn][i] + b, 0.0f) * s);
        } else {
#pragma unroll
          for (int i = 0; i < 4; i++)
            Ql[(size_t)(rg + i) * HD + cg] = f2bf(fmaxf(acc[fm][fn][i] + b, 0.0f));
        }
      }
  }
}

// ------------- logits = Ql @ Ks^T : [2048,2048] f32, BN=64, 512 blocks -------------
__global__ __launch_bounds__(512, 4)
void gemm_logits(const unsigned short* __restrict__ Ql, const unsigned short* __restrict__ Ks,
                 float* __restrict__ C) {
  __shared__ __align__(16) unsigned short lds[3 * 12288];  // 72 KB
  const int bid = blockIdx.x;
  const int x = bid & 7, j = bid >> 3;     // 64 per XCD
  const int bm = (x & 3) * 4 + (j >> 4);   // [0,16) M-panel (128 rows)
  const int bn = (x >> 2) * 16 + (j & 15); // [0,32) 64-wide N-panel

  f32x4 acc[2][2];
  mfma_pipeline<64, 16>(Ql + (size_t)bm * 128 * HD, Ks + (size_t)bn * 64 * HD, HD, HD, lds, acc);

  const int tid = threadIdx.x;
  const int lane = tid & 63, wave = tid >> 6;
  const int wr = wave >> 1, wc = wave & 1;
  const int l15 = lane & 15, hi = lane >> 4;
  const int row0 = bm * 128 + wr * 32;
  const int col0 = bn * 64 + wc * 32;
#pragma unroll
  for (int fm = 0; fm < 2; fm++)
#pragma unroll
    for (int fn = 0; fn < 2; fn++) {
      int cg = col0 + fn * 16 + l15;
      int rg = row0 + fm * 16 + hi * 4;
#pragma unroll
      for (int i = 0; i < 4; i++)
        C[(size_t)(rg + i) * TK + cg] = acc[fm][fn][i];
    }
}

// ------------- PV (BN=64, 256 blocks) || attn.T transpose (256 blocks x 4 tiles) ---
__global__ __launch_bounds__(512, 4)
void pv_and_transpose(const unsigned short* __restrict__ attnb, const unsigned short* __restrict__ VT,
                      float* __restrict__ outp, float* __restrict__ attnT) {
  __shared__ __align__(16) unsigned short lds[3 * 12288];  // 72 KB
  const int bid = blockIdx.x;
  const int tid = threadIdx.x;
  if (bid < 256) {
    const int x = bid & 7, j = bid >> 3;    // 32 per XCD
    const int bm = (x & 3) * 4 + (j >> 3);  // [0,16) M-panel (128 rows)
    const int bn = (x >> 2) * 8 + (j & 7);  // [0,16) 64-wide N-panel
    f32x4 acc[2][2];
    mfma_pipeline<64, 32>(attnb + (size_t)bm * 128 * TK, VT + (size_t)bn * 64 * TK,
                          TK, TK, lds, acc);
    const int lane = tid & 63, wave = tid >> 6;
    const int wr = wave >> 1, wc = wave & 1;
    const int l15 = lane & 15, hi = lane >> 4;
    const int row0 = bm * 128 + wr * 32;
    const int col0 = bn * 64 + wc * 32;
#pragma unroll
    for (int fm = 0; fm < 2; fm++)
#pragma unroll
      for (int fn = 0; fn < 2; fn++) {
        int cg = col0 + fn * 16 + l15;
        int rg = row0 + fm * 16 + hi * 4;
#pragma unroll
        for (int i = 0; i < 4; i++)
          outp[(size_t)(rg + i) * HD + cg] = acc[fm][fn][i];
      }
  } else {
    // transpose: bf16 attn [TQ][TK] -> f32 attn.T [TK][TQ]; 4 tiles of 64x64 each
    unsigned short (*tile)[68] = reinterpret_cast<unsigned short (*)[68]>(lds);
#pragma unroll 1
    for (int it = 0; it < 4; ++it) {
      if (it) __syncthreads();
      const int q0 = (bid - 256) * 4 + it;
      const int tr = (q0 >> 5) * 64;   // source row block
      const int tc = (q0 & 31) * 64;   // source col block
#pragma unroll
      for (int i = 0; i < 2; i++) {
        int q = i * 512 + tid;
        int r = q >> 4;
        int c4 = (q & 15) * 4;
        u16x4 v = *(const u16x4*)(attnb + (size_t)(tr + r) * TK + tc + c4);
        *(u16x4*)(&tile[r][c4]) = v;
      }
      __syncthreads();
#pragma unroll
      for (int i = 0; i < 2; i++) {
        int q = i * 512 + tid;
        int c = q >> 4;
        int r4 = (q & 15) * 4;
        f32x4 o;
#pragma unroll
        for (int jx = 0; jx < 4; jx++) o[jx] = bf2f(tile[r4 + jx][c]);
        *(f32x4*)(attnT + (size_t)(tc + c) * TQ + tr + r4) = o;
      }
    }
  }
}

// ------------- row softmax over 2048 logits -> bf16 attn (4 rows/block) ------------
__global__ __launch_bounds__(256)
void softmax_k(const float* __restrict__ logits, unsigned short* __restrict__ attnb) {
  const int tid = threadIdx.x;
  const int lane = tid & 63;
  const int wave = tid >> 6;
  __shared__ float redm[4], reds[4];
  const float L2E = 1.44269504088896341f;

#pragma unroll 1
  for (int rr = 0; rr < 4; ++rr) {
    const int row = blockIdx.x * 4 + rr;
    const float* lr = logits + (size_t)row * TK;

    f32x4 v0 = *(const f32x4*)(lr + tid * 8);
    f32x4 v1 = *(const f32x4*)(lr + tid * 8 + 4);
    float x[8];
#pragma unroll
    for (int j = 0; j < 4; j++) { x[j] = v0[j]; x[4 + j] = v1[j]; }

    float m = x[0];
#pragma unroll
    for (int j = 1; j < 8; j++) m = fmaxf(m, x[j]);
    for (int o = 32; o > 0; o >>= 1) m = fmaxf(m, __shfl_xor(m, o));
    if (rr) __syncthreads();                  // protect redm/reds reuse
    if (lane == 0) redm[wave] = m;
    __syncthreads();
    m = fmaxf(fmaxf(redm[0], redm[1]), fmaxf(redm[2], redm[3]));

    float e[8];
    float s = 0.0f;
#pragma unroll
    for (int j = 0; j < 8; j++) { e[j] = exp2f((x[j] - m) * L2E); s += e[j]; }
    for (int o = 32; o > 0; o >>= 1) s += __shfl_xor(s, o);
    if (lane == 0) reds[wave] = s;
    __syncthreads();
    s = reds[0] + reds[1] + reds[2] + reds[3];
    float inv = 1.0f / s;

    unsigned short* ar = attnb + (size_t)row * TK;
    u16x4 o0, o1;
#pragma unroll
    for (int j = 0; j < 4; j++) { o0[j] = f2bf(e[j] * inv); o1[j] = f2bf(e[4 + j] * inv); }
    *(u16x4*)(ar + tid * 8) = o0;
    *(u16x4*)(ar + tid * 8 + 4) = o1;
  }
}

// ------------- f32 -> bf16 converts: 1152 blocks, 8 f32x4 per thread ---------------
__global__ __launch_bounds__(256)
void cvt6x(const float* __restrict__ Q, const float* __restrict__ K, const float* __restrict__ V,
           const float* __restrict__ Wq, const float* __restrict__ Wk, const float* __restrict__ Wv,
           unsigned short* __restrict__ Qb, unsigned short* __restrict__ Kb,
           unsigned short* __restrict__ Vb, unsigned short* __restrict__ Wqb,
           unsigned short* __restrict__ Wkb, unsigned short* __restrict__ Wvb) {
  const int bid = blockIdx.x;
  const int tid = threadIdx.x;
  const float* src;
  unsigned short* dst;
  int base4;
  if (bid < 768) {                           // Q/K/V: 256 blocks each, 524288 f32x4
    const int m = bid >> 8, b = bid & 255;
    src = (m == 0) ? Q : (m == 1) ? K : V;
    dst = (m == 0) ? Qb : (m == 1) ? Kb : Vb;
    base4 = b * 2048;
  } else {                                   // W: 128 blocks each, 262144 f32x4
    const int w = bid - 768;
    const int m = w >> 7, b = w & 127;
    src = (m == 0) ? Wq : (m == 1) ? Wk : Wv;
    dst = (m == 0) ? Wqb : (m == 1) ? Wkb : Wvb;
    base4 = b * 2048;
  }
#pragma unroll
  for (int u = 0; u < 8; u++) {
    const int idx4 = base4 + u * 256 + tid;
    f32x4 v = *(const f32x4*)(src + (size_t)idx4 * 4);
    u16x4 o;
#pragma unroll
    for (int jj = 0; jj < 4; jj++) o[jj] = f2bf(v[jj]);
    *(u16x4*)(dst + (size_t)idx4 * 4) = o;
  }
}

extern "C" void kernel_launch(void* const* d_in, const int* in_sizes, int n_in,
                              void* d_out, int out_size, void* d_ws, size_t ws_size,
                              hipStream_t stream) {
  const float* Q  = (const float*)d_in[0];
  const float* K  = (const float*)d_in[1];
  const float* V  = (const float*)d_in[2];
  const float* Wq = (const float*)d_in[3];
  const float* bq = (const float*)d_in[4];
  const float* Wk = (const float*)d_in[5];
  const float* bk = (const float*)d_in[6];
  const float* Wv = (const float*)d_in[7];
  const float* bv = (const float*)d_in[8];
  const float* Wo = (const float*)d_in[9];
  // bo unused: softmax shift-invariant.

  uint8_t* w = (uint8_t*)d_ws;
  unsigned short* Qb  = (unsigned short*)(w + 0);            // 4 MB
  unsigned short* Kb  = (unsigned short*)(w + 4194304);      // 4 MB
  unsigned short* Vb  = (unsigned short*)(w + 8388608);      // 4 MB
  unsigned short* Wqb = (unsigned short*)(w + 12582912);     // 2 MB
  unsigned short* Wkb = (unsigned short*)(w + 14680064);     // 2 MB
  unsigned short* Wvb = (unsigned short*)(w + 16777216);     // 2 MB
  unsigned short* Ql  = (unsigned short*)(w + 18874368);     // 4 MB
  unsigned short* Ks  = (unsigned short*)(w + 23068672);     // 4 MB
  unsigned short* VT  = (unsigned short*)(w + 27262976);     // 4 MB
  float*          logits = (float*)(w + 31457280);           // 16 MB
  unsigned short* attnb  = (unsigned short*)(w + 48234496);  // 8 MB
  // total 56,623,104 bytes

  float* outp  = (float*)d_out;              // [2048][1024]
  float* attnT = outp + (size_t)TQ * HD;     // [2048][2048]

  // converts: 1152 blocks, 128 B/thread
  cvt6x<<<dim3(1152), dim3(256), 0, stream>>>(Q, K, V, Wq, Wk, Wv,
                                              Qb, Kb, Vb, Wqb, Wkb, Wvb);

  // projections: M=2048, N=1024, K=1024, z in {Q,K,V}; 768 blocks = 3/CU balanced
  gemm_proj<<<dim3(768), dim3(512), 0, stream>>>(Qb, Kb, Vb, Wqb, Wkb, Wvb,
                                                 bq, bk, bv, Wo, Ql, Ks, VT);

  // logits: M=2048, N=2048, K=1024; BN=64 -> 512 blocks = 2/CU uniform
  gemm_logits<<<dim3(512), dim3(512), 0, stream>>>(Ql, Ks, logits);

  // softmax: 512 blocks x 4 rows
  softmax_k<<<dim3(512), dim3(256), 0, stream>>>(logits, attnb);

  // PV (256 blocks) || transpose (256 blocks x 4 tiles) = 512 blocks = 2/CU
  pv_and_transpose<<<dim3(512), dim3(512), 0, stream>>>(attnb, VT, outp, attnT);
}

// Round 16
// 67.618 us; speedup vs baseline: 1.0134x; 1.0134x over previous
//
#include <hip/hip_runtime.h>
#include <stdint.h>

// Multihead_Attention on MI355X (gfx950). R14 configuration (67.67 µs session
// best; R15's micro-consolidation regressed and is reverted).
// cvt6x (6912 blocks) -> proj (relu, Wo/8 folded into K cols, V transposed via
// LDS epilogue; BN=64, 768 blocks = 3/CU) -> logits GEMM (BN=64, 512 blocks =
// 2/CU) -> softmax (2048 blocks) -> [PV (BN=64, 256 blocks) || attn.T transpose
// (1024 blocks)].
// GEMM core: bf16 MFMA 16x16x32, BK=64, 512 thr, 3-buffer LDS / 1 barrier/iter,
// stage-before-compute (2-iter prefetch), global_load_lds w16, counted vmcnt
// (T3+T4), setprio (T5), XOR chunk swizzle, XCD rect swizzle.

#define TQ 2048
#define TK 2048
#define HD 1024

#define DEVI __device__ __forceinline__

typedef __attribute__((ext_vector_type(8))) short bf16x8;
typedef __attribute__((ext_vector_type(4))) float f32x4;
typedef __attribute__((ext_vector_type(4))) unsigned short u16x4;

DEVI unsigned short f2bf(float f) {
  uint32_t u = __builtin_bit_cast(uint32_t, f);
  u += 0x7FFFu + ((u >> 16) & 1u);
  return (unsigned short)(u >> 16);
}
DEVI float bf2f(unsigned short h) {
  uint32_t u = ((uint32_t)h) << 16;
  return __builtin_bit_cast(float, u);
}
DEVI void gload_lds16(const void* g, void* l) {
  __builtin_amdgcn_global_load_lds((const __attribute__((address_space(1))) void*)g,
                                   (__attribute__((address_space(3))) void*)l,
                                   16, 0, 0);
}
template<int N> DEVI void wait_vm() { asm volatile("s_waitcnt vmcnt(%0)" :: "n"(N) : "memory"); }
DEVI void wait_lgkm0() { asm volatile("s_waitcnt lgkmcnt(0)" ::: "memory"); }
#define SBAR() __builtin_amdgcn_s_barrier()

// ---- stage one K-step tile pair (A 128x64, B BNx64 bf16) into one LDS buffer.
// 512 threads. Linear LDS dest (gload_lds requirement), source col XOR-swizzled.
template<int BN>
DEVI void stageT(const unsigned short* __restrict__ A, const unsigned short* __restrict__ B,
                 int lda, int ldb, int k0, unsigned short* buf, int tid) {
#pragma unroll
  for (int i = 0; i < 2; i++) {              // A: 128 rows x 8 chunks = 1024 chunks
    int c = i * 512 + tid;
    int r = c >> 3;
    int cs = (c & 7) ^ (r & 7);
    gload_lds16(A + (size_t)r * lda + k0 + cs * 8, buf + c * 8);
  }
#pragma unroll
  for (int i = 0; i < BN / 64; i++) {        // B: BN rows x 8 chunks
    int c = i * 512 + tid;
    int r = c >> 3;
    int cs = (c & 7) ^ (r & 7);
    gload_lds16(B + (size_t)r * ldb + k0 + cs * 8, buf + 8192 + c * 8);
  }
}

// ---- one staged 64-K-step. BN=128: wave 64x32 (acc[4][2]); BN=64: 32x32 (acc[2][2]).
template<int BN>
DEVI void computeT(const unsigned short* lA, const unsigned short* lB, f32x4 (*acc)[2],
                   int wr, int wc, int l15, int hi) {
  constexpr int FM = (BN == 128) ? 4 : 2;
  constexpr int WMR = (BN == 128) ? 64 : 32;
#pragma unroll
  for (int kk = 0; kk < 2; kk++) {
    bf16x8 af[4], bfr[2];
#pragma unroll
    for (int f = 0; f < FM; f++) {
      int ra = wr * WMR + f * 16 + l15;
      int ca = (kk * 4 + hi) ^ (ra & 7);
      af[f] = *(const bf16x8*)(lA + ra * 64 + ca * 8);
    }
#pragma unroll
    for (int f = 0; f < 2; f++) {
      int rb = wc * 32 + f * 16 + l15;
      int cb = (kk * 4 + hi) ^ (rb & 7);
      bfr[f] = *(const bf16x8*)(lB + rb * 64 + cb * 8);
    }
#pragma unroll
    for (int fm = 0; fm < FM; fm++)
#pragma unroll
      for (int fn = 0; fn < 2; fn++)
        acc[fm][fn] = __builtin_amdgcn_mfma_f32_16x16x32_bf16(af[fm], bfr[fn], acc[fm][fn], 0, 0, 0);
  }
}

// ---- 3-buffer pipeline, counted vmcnt, ONE barrier/iter, stage-before-compute.
// Ledger: RAW — wave Y's wait_vm<LPS> at iter t retires its stage(t) loads (only
// stage(t+1) outstanding) before Y enters SBAR(t); readers proceed after SBAR(t).
// WAR — stage(t+2) overwrites buf[(t-1)%3]; each wave's reads of it drained at its
// lgkm0 (end of iter t-1), which precedes its SBAR(t); the stage is issued only
// after SBAR(t). WAW — distinct buffers within any 2-deep window.
template<int BN, int NKT>
DEVI void mfma_pipeline(const unsigned short* __restrict__ A, const unsigned short* __restrict__ B,
                        int lda, int ldb, unsigned short* lds, f32x4 (*acc)[2]) {
  constexpr int FM = (BN == 128) ? 4 : 2;
  constexpr int LPS = 2 + BN / 64;           // loads per stage per thread (4 or 3)
  constexpr int BSTR = 8192 + BN * 64;       // buffer stride in shorts
  const int tid = threadIdx.x;
  const int lane = tid & 63, wave = tid >> 6;
  const int l15 = lane & 15, hi = lane >> 4;
  const int wr = (BN == 128) ? (wave >> 2) : (wave >> 1);
  const int wc = (BN == 128) ? (wave & 3) : (wave & 1);

#pragma unroll
  for (int i = 0; i < FM; i++)
#pragma unroll
    for (int j = 0; j < 2; j++) acc[i][j] = (f32x4)(0.0f);

  stageT<BN>(A, B, lda, ldb, 0, lds, tid);
  stageT<BN>(A, B, lda, ldb, 64, lds + BSTR, tid);

  int cur = 0, nxt = 2;                      // t%3 and (t+2)%3 counters
#pragma unroll 1
  for (int t = 0; t < NKT; ++t) {
    if (t < NKT - 1) wait_vm<LPS>();
    else wait_vm<0>();
    SBAR();                                   // buf t ready on every wave
    unsigned short* buf = lds + cur * BSTR;
    if (t + 2 < NKT) stageT<BN>(A, B, lda, ldb, (t + 2) * 64, lds + nxt * BSTR, tid);
    __builtin_amdgcn_s_setprio(1);
    computeT<BN>(buf, buf + 8192, acc, wr, wc, l15, hi);
    __builtin_amdgcn_s_setprio(0);
    wait_lgkm0();                             // my ds_reads drained (WAR release)
    cur = (cur == 2) ? 0 : cur + 1;
    nxt = (nxt == 2) ? 0 : nxt + 1;
  }
}

// ------------- batched projection: relu(X @ W^T + b), BN=64, 768 blocks ------------
__global__ __launch_bounds__(512, 4)
void gemm_proj(const unsigned short* __restrict__ Qb, const unsigned short* __restrict__ Kb,
               const unsigned short* __restrict__ Vb,
               const unsigned short* __restrict__ Wqb, const unsigned short* __restrict__ Wkb,
               const unsigned short* __restrict__ Wvb,
               const float* __restrict__ bq, const float* __restrict__ bk,
               const float* __restrict__ bv, const float* __restrict__ Wo,
               unsigned short* __restrict__ Ql, unsigned short* __restrict__ Ks,
               unsigned short* __restrict__ VT) {
  __shared__ __align__(16) unsigned short lds[3 * 12288];  // 72 KB
  const int bid = blockIdx.x;
  const int x = bid & 7, j = bid >> 3;       // XCD, index within (96 per XCD)
  const int z = j >> 5;                      // matrix select (32 tiles per z per XCD)
  const int jj = j & 31;
  const int bm = (x & 3) * 4 + (jj >> 3);    // [0,16) M-panel (128 rows)
  const int bn = (x >> 2) * 8 + (jj & 7);    // [0,16) 64-wide N-panel

  const unsigned short* A = (z == 0) ? Qb : (z == 1) ? Kb : Vb;
  const unsigned short* B = (z == 0) ? Wqb : (z == 1) ? Wkb : Wvb;
  const float* bias = (z == 0) ? bq : (z == 1) ? bk : bv;

  f32x4 acc[2][2];
  mfma_pipeline<64, 16>(A + (size_t)bm * 128 * HD, B + (size_t)bn * 64 * HD, HD, HD, lds, acc);

  const int tid = threadIdx.x;
  const int lane = tid & 63, wave = tid >> 6;
  const int wr = wave >> 1, wc = wave & 1;
  const int l15 = lane & 15, hi = lane >> 4;
  const int row0 = bm * 128 + wr * 32;
  const int col0 = bn * 64 + wc * 32;

  if (z == 2) {
    // V: LDS-transpose the 128x64 output tile -> coalesced VT row stores.
    __syncthreads();                          // all MFMA reads done before reuse
    unsigned short (*T)[132] = reinterpret_cast<unsigned short (*)[132]>(lds);
#pragma unroll
    for (int fm = 0; fm < 2; fm++)
#pragma unroll
      for (int fn = 0; fn < 2; fn++) {
        int cl = wc * 32 + fn * 16 + l15;     // local col [0,64)
        float b = bias[bn * 64 + cl];
#pragma unroll
        for (int i = 0; i < 4; i++)
          T[cl][wr * 32 + fm * 16 + hi * 4 + i] = f2bf(fmaxf(acc[fm][fn][i] + b, 0.0f));
      }
    __syncthreads();
#pragma unroll
    for (int i = 0; i < 4; i++) {
      int h = i * 512 + tid;                  // 2048 u16x4 chunks
      int c = h >> 5;                         // [0,64) local col -> VT row
      int rq = h & 31;                        // quad within 128-row run
      u16x4 v = *(const u16x4*)(&T[c][rq * 4]);
      *(u16x4*)(VT + (size_t)(bn * 64 + c) * TK + bm * 128 + rq * 4) = v;
    }
  } else {
#pragma unroll
    for (int fm = 0; fm < 2; fm++)
#pragma unroll
      for (int fn = 0; fn < 2; fn++) {
        int cg = col0 + fn * 16 + l15;
        int rg = row0 + fm * 16 + hi * 4;
        float b = bias[cg];
        if (z == 1) {
          float s = 0.125f * Wo[cg >> 6];     // fold Wo/sqrt(64) into K columns
#pragma unroll
          for (int i = 0; i < 4; i++)
            Ks[(size_t)(rg + i) * HD + cg] = f2bf(fmaxf(acc[fm][fn][i] + b, 0.0f) * s);
        } else {
#pragma unroll
          for (int i = 0; i < 4; i++)
            Ql[(size_t)(rg + i) * HD + cg] = f2bf(fmaxf(acc[fm][fn][i] + b, 0.0f));
        }
      }
  }
}

// ------------- logits = Ql @ Ks^T : [2048,2048] f32, BN=64, 512 blocks -------------
__global__ __launch_bounds__(512, 4)
void gemm_logits(const unsigned short* __restrict__ Ql, const unsigned short* __restrict__ Ks,
                 float* __restrict__ C) {
  __shared__ __align__(16) unsigned short lds[3 * 12288];  // 72 KB
  const int bid = blockIdx.x;
  const int x = bid & 7, j = bid >> 3;     // 64 per XCD
  const int bm = (x & 3) * 4 + (j >> 4);   // [0,16) M-panel (128 rows)
  const int bn = (x >> 2) * 16 + (j & 15); // [0,32) 64-wide N-panel

  f32x4 acc[2][2];
  mfma_pipeline<64, 16>(Ql + (size_t)bm * 128 * HD, Ks + (size_t)bn * 64 * HD, HD, HD, lds, acc);

  const int tid = threadIdx.x;
  const int lane = tid & 63, wave = tid >> 6;
  const int wr = wave >> 1, wc = wave & 1;
  const int l15 = lane & 15, hi = lane >> 4;
  const int row0 = bm * 128 + wr * 32;
  const int col0 = bn * 64 + wc * 32;
#pragma unroll
  for (int fm = 0; fm < 2; fm++)
#pragma unroll
    for (int fn = 0; fn < 2; fn++) {
      int cg = col0 + fn * 16 + l15;
      int rg = row0 + fm * 16 + hi * 4;
#pragma unroll
      for (int i = 0; i < 4; i++)
        C[(size_t)(rg + i) * TK + cg] = acc[fm][fn][i];
    }
}

// ------------- PV (BN=64, 256 blocks, full K=2048) || attn.T transpose (1024) ------
__global__ __launch_bounds__(512, 4)
void pv_and_transpose(const unsigned short* __restrict__ attnb, const unsigned short* __restrict__ VT,
                      float* __restrict__ outp, float* __restrict__ attnT) {
  __shared__ __align__(16) unsigned short lds[3 * 12288];  // 72 KB
  const int bid = blockIdx.x;
  const int tid = threadIdx.x;
  if (bid < 256) {
    const int x = bid & 7, j = bid >> 3;    // 32 per XCD
    const int bm = (x & 3) * 4 + (j >> 3);  // [0,16) M-panel (128 rows)
    const int bn = (x >> 2) * 8 + (j & 7);  // [0,16) 64-wide N-panel
    f32x4 acc[2][2];
    mfma_pipeline<64, 32>(attnb + (size_t)bm * 128 * TK, VT + (size_t)bn * 64 * TK,
                          TK, TK, lds, acc);
    const int lane = tid & 63, wave = tid >> 6;
    const int wr = wave >> 1, wc = wave & 1;
    const int l15 = lane & 15, hi = lane >> 4;
    const int row0 = bm * 128 + wr * 32;
    const int col0 = bn * 64 + wc * 32;
#pragma unroll
    for (int fm = 0; fm < 2; fm++)
#pragma unroll
      for (int fn = 0; fn < 2; fn++) {
        int cg = col0 + fn * 16 + l15;
        int rg = row0 + fm * 16 + hi * 4;
#pragma unroll
        for (int i = 0; i < 4; i++)
          outp[(size_t)(rg + i) * HD + cg] = acc[fm][fn][i];
      }
  } else {
    // transpose: bf16 attn [TQ][TK] tile (64x64) -> f32 attn.T [TK][TQ]
    unsigned short (*tile)[68] = reinterpret_cast<unsigned short (*)[68]>(lds);
    const int q0 = bid - 256;
    const int tr = (q0 >> 5) * 64;   // source row block
    const int tc = (q0 & 31) * 64;   // source col block
#pragma unroll
    for (int i = 0; i < 2; i++) {
      int q = i * 512 + tid;
      int r = q >> 4;
      int c4 = (q & 15) * 4;
      u16x4 v = *(const u16x4*)(attnb + (size_t)(tr + r) * TK + tc + c4);
      *(u16x4*)(&tile[r][c4]) = v;
    }
    __syncthreads();
#pragma unroll
    for (int i = 0; i < 2; i++) {
      int q = i * 512 + tid;
      int c = q >> 4;
      int r4 = (q & 15) * 4;
      f32x4 o;
#pragma unroll
      for (int jx = 0; jx < 4; jx++) o[jx] = bf2f(tile[r4 + jx][c]);
      *(f32x4*)(attnT + (size_t)(tc + c) * TQ + tr + r4) = o;
    }
  }
}

// ------------- row softmax over 2048 logits -> bf16 attn ---------------------------
__global__ __launch_bounds__(256)
void softmax_k(const float* __restrict__ logits, unsigned short* __restrict__ attnb) {
  const int row = blockIdx.x;
  const int tid = threadIdx.x;
  const int lane = tid & 63;
  const int wave = tid >> 6;
  const float* lr = logits + (size_t)row * TK;

  f32x4 v0 = *(const f32x4*)(lr + tid * 8);
  f32x4 v1 = *(const f32x4*)(lr + tid * 8 + 4);
  float x[8];
#pragma unroll
  for (int j = 0; j < 4; j++) { x[j] = v0[j]; x[4 + j] = v1[j]; }

  float m = x[0];
#pragma unroll
  for (int j = 1; j < 8; j++) m = fmaxf(m, x[j]);
  for (int o = 32; o > 0; o >>= 1) m = fmaxf(m, __shfl_xor(m, o));
  __shared__ float redm[4], reds[4];
  if (lane == 0) redm[wave] = m;
  __syncthreads();
  m = fmaxf(fmaxf(redm[0], redm[1]), fmaxf(redm[2], redm[3]));

  const float L2E = 1.44269504088896341f;
  float e[8];
  float s = 0.0f;
#pragma unroll
  for (int j = 0; j < 8; j++) { e[j] = exp2f((x[j] - m) * L2E); s += e[j]; }
  for (int o = 32; o > 0; o >>= 1) s += __shfl_xor(s, o);
  if (lane == 0) reds[wave] = s;
  __syncthreads();
  s = reds[0] + reds[1] + reds[2] + reds[3];
  float inv = 1.0f / s;

  unsigned short* ar = attnb + (size_t)row * TK;
  u16x4 o0, o1;
#pragma unroll
  for (int j = 0; j < 4; j++) { o0[j] = f2bf(e[j] * inv); o1[j] = f2bf(e[4 + j] * inv); }
  *(u16x4*)(ar + tid * 8) = o0;
  *(u16x4*)(ar + tid * 8 + 4) = o1;
}

// ------------- f32 -> bf16 converts ------------------------------------------------
__global__ __launch_bounds__(256)
void cvt6x(const float* __restrict__ Q, const float* __restrict__ K, const float* __restrict__ V,
           const float* __restrict__ Wq, const float* __restrict__ Wk, const float* __restrict__ Wv,
           unsigned short* __restrict__ Qb, unsigned short* __restrict__ Kb,
           unsigned short* __restrict__ Vb, unsigned short* __restrict__ Wqb,
           unsigned short* __restrict__ Wkb, unsigned short* __restrict__ Wvb) {
  const int bid = blockIdx.x;
  const int tid = threadIdx.x;
  if (bid < 6144) {
    const int x = bid & 7, k = bid >> 3;     // x = XCD, k in [0,768)
    const int rb = x * 6 + (k % 6);          // row-panel [0,48)
    const int s = k / 6;                     // slice [0,128)
    const int m = rb >> 4;                   // matrix select
    const int r0 = (rb & 15) * 128;          // first row within matrix
    const float* src = (m == 0) ? Q : (m == 1) ? K : V;
    unsigned short* dst = (m == 0) ? Qb : (m == 1) ? Kb : Vb;
    const int idx4 = r0 * 256 + s * 256 + tid;   // f32x4 index
    f32x4 v = *(const f32x4*)(src + idx4 * 4);
    u16x4 o;
#pragma unroll
    for (int jj = 0; jj < 4; jj++) o[jj] = f2bf(v[jj]);
    *(u16x4*)(dst + idx4 * 4) = o;
  } else {
    const int w = bid - 6144;                // [0,768)
    const int m = w >> 8;                    // matrix select
    const int b = w & 255;
    const float* src = (m == 0) ? Wq : (m == 1) ? Wk : Wv;
    unsigned short* dst = (m == 0) ? Wqb : (m == 1) ? Wkb : Wvb;
#pragma unroll
    for (int u = 0; u < 4; u++) {
      const int idx4 = b * 1024 + u * 256 + tid;
      f32x4 v = *(const f32x4*)(src + idx4 * 4);
      u16x4 o;
#pragma unroll
      for (int jj = 0; jj < 4; jj++) o[jj] = f2bf(v[jj]);
      *(u16x4*)(dst + idx4 * 4) = o;
    }
  }
}

extern "C" void kernel_launch(void* const* d_in, const int* in_sizes, int n_in,
                              void* d_out, int out_size, void* d_ws, size_t ws_size,
                              hipStream_t stream) {
  const float* Q  = (const float*)d_in[0];
  const float* K  = (const float*)d_in[1];
  const float* V  = (const float*)d_in[2];
  const float* Wq = (const float*)d_in[3];
  const float* bq = (const float*)d_in[4];
  const float* Wk = (const float*)d_in[5];
  const float* bk = (const float*)d_in[6];
  const float* Wv = (const float*)d_in[7];
  const float* bv = (const float*)d_in[8];
  const float* Wo = (const float*)d_in[9];
  // bo unused: softmax shift-invariant.

  uint8_t* w = (uint8_t*)d_ws;
  unsigned short* Qb  = (unsigned short*)(w + 0);            // 4 MB
  unsigned short* Kb  = (unsigned short*)(w + 4194304);      // 4 MB
  unsigned short* Vb  = (unsigned short*)(w + 8388608);      // 4 MB
  unsigned short* Wqb = (unsigned short*)(w + 12582912);     // 2 MB
  unsigned short* Wkb = (unsigned short*)(w + 14680064);     // 2 MB
  unsigned short* Wvb = (unsigned short*)(w + 16777216);     // 2 MB
  unsigned short* Ql  = (unsigned short*)(w + 18874368);     // 4 MB
  unsigned short* Ks  = (unsigned short*)(w + 23068672);     // 4 MB
  unsigned short* VT  = (unsigned short*)(w + 27262976);     // 4 MB
  float*          logits = (float*)(w + 31457280);           // 16 MB
  unsigned short* attnb  = (unsigned short*)(w + 48234496);  // 8 MB
  // total 56,623,104 bytes

  float* outp  = (float*)d_out;              // [2048][1024]
  float* attnT = outp + (size_t)TQ * HD;     // [2048][2048]

  // converts
  cvt6x<<<dim3(6912), dim3(256), 0, stream>>>(Q, K, V, Wq, Wk, Wv,
                                              Qb, Kb, Vb, Wqb, Wkb, Wvb);

  // projections: M=2048, N=1024, K=1024, z in {Q,K,V}; 768 blocks = 3/CU balanced
  gemm_proj<<<dim3(768), dim3(512), 0, stream>>>(Qb, Kb, Vb, Wqb, Wkb, Wvb,
                                                 bq, bk, bv, Wo, Ql, Ks, VT);

  // logits: M=2048, N=2048, K=1024; BN=64 -> 512 blocks = 2/CU uniform
  gemm_logits<<<dim3(512), dim3(512), 0, stream>>>(Ql, Ks, logits);

  softmax_k<<<dim3(TQ), dim3(256), 0, stream>>>(logits, attnb);

  // PV (M=2048, N=1024, K=2048; BN=64 -> 256 blocks, full machine)
  // || transpose (1024 blocks) — PV blocks first so every CU gets one at t=0
  pv_and_transpose<<<dim3(1280), dim3(512), 0, stream>>>(attnb, VT, outp, attnT);
}